// Round 3
// baseline (410.427 us; speedup 1.0000x reference)
//
#include <hip/hip_runtime.h>
#include <hip/hip_bf16.h>

// TopKRouter: logits = x[16384,4096] @ W[64,4096]^T; softmax; top-2; z_loss.
// v3: fully fused. Exact 3-way bf16 split GEMM (6 MFMA products == fp32).
//  - One block = 32 tokens, 4 waves each owning a private K=1024 chunk.
//  - NO __syncthreads in the K-loop: per-wave LDS dbuf staging gated by an
//    explicit per-wave s_waitcnt vmcnt(0) (0x0F70). Waves free-run; the
//    round-2 all-wave barrier drain (m97-plateau failure mode) is gone.
//  - K-partials reduced in LDS at the end; softmax/top-2/z computed in-block
//    (removes the 16 MiB logits round-trip + separate epilogue kernel).
//  - z partial per block -> zbuf -> tiny zreduce (round-1 lesson: never
//    same-address atomics).

typedef __bf16  bf16x8  __attribute__((ext_vector_type(8)));
typedef float   f32x16  __attribute__((ext_vector_type(16)));

#define BS_TOK 16384              // B*S tokens
#define H_DIM  4096
#define E_DIM  64
#define MT     32                 // tokens per block
#define KWAVE  1024               // K floats per wave (4 waves x 1024 = 4096)
#define NPANEL 16                 // panels of 64 floats per wave
#define WS_ZBUF_OFF (1536u << 10) // z partials at +1.5 MiB in d_ws

__device__ __forceinline__ void split3(float v, __bf16 &b0, __bf16 &b1, __bf16 &b2) {
    b0 = (__bf16)v;            // top 8 mantissa bits (RN)
    float r = v - (float)b0;   // exact in fp32
    b1 = (__bf16)r;            // next 8 bits
    float r2 = r - (float)b1;  // exact
    b2 = (__bf16)r2;           // v == b0+b1+b2 (within fp32)
}

__device__ __forceinline__ void async_copy16(const float* gp, float* lp) {
    __builtin_amdgcn_global_load_lds(
        (const __attribute__((address_space(1))) void*)gp,
        (__attribute__((address_space(3))) void*)lp, 16, 0, 0);
}

// Kernel 0: split gate_w into 3 bf16 terms in 32x32x16 MFMA B-frag order.
// frag f = kb*6 + nt*3 + term; element [f*64 + lane].
// lane holds W_term[n = nt*32 + (lane&31)][k = kb*16 + (lane>>5)*8 + j]
__global__ void prep_w(const float* __restrict__ gw, bf16x8* __restrict__ wb) {
    int idx  = blockIdx.x * blockDim.x + threadIdx.x;   // 0..32767
    int kb   = idx >> 7;
    int rem  = idx & 127;
    int nt   = rem >> 6;
    int lane = rem & 63;
    int n  = nt * 32 + (lane & 31);
    int kk = kb * 16 + ((lane >> 5) << 3);
    const float* p = gw + (size_t)n * H_DIM + kk;
    bf16x8 t0, t1, t2;
#pragma unroll
    for (int j = 0; j < 8; ++j) {
        __bf16 a, b, c;
        split3(p[j], a, b, c);
        t0[j] = a; t1[j] = b; t2[j] = c;
    }
    size_t fb = (size_t)(kb * 2 + nt) * 3;
    wb[(fb + 0) * 64 + lane] = t0;
    wb[(fb + 1) * 64 + lane] = t1;
    wb[(fb + 2) * 64 + lane] = t2;
}

// Kernel 1: fused router. 512 blocks x 256 thr (2 blocks/CU, 64 KiB LDS).
// Wave w: K-chunk [w*1024, w*1024+1024) of rows m0..m0+31. Panel = 32 rows
// x 64 floats staged as 8 async 1-KiB rounds; chunk c of row g lands at slot
// c ^ (g&15) (16B XOR swizzle -> ds_read_b128 at the 8-lane/bank-quad floor).
__global__ __launch_bounds__(256, 2) void fused_router(
        const float* __restrict__ x, const bf16x8* __restrict__ wb,
        float* __restrict__ out, float* __restrict__ zbuf) {
    __shared__ float lds[16384];   // 4 waves x dbuf(2 x 2048 floats) = 64 KiB
    __shared__ float zsh[4];

    int tid = threadIdx.x;
    int w   = tid >> 6;            // wave 0..3 (owns K-chunk w)
    int l   = tid & 63;
    int m0  = blockIdx.x * MT;
    float* sw = &lds[w * 4096];    // this wave's staging dbuf

    // global pointers: round r covers rows 4r..4r+3, 16 chunks of 16 B each
    const float* gp[8];
#pragma unroll
    for (int r = 0; r < 8; ++r) {
        int g = 4 * r + (l >> 4);                  // row in tile 0..31
        int c = (l & 15) ^ (g & 15);               // swizzled global chunk
        gp[r] = x + (size_t)(m0 + g) * H_DIM + w * KWAVE + c * 4;
    }

    f32x16 acc0, acc1;
#pragma unroll
    for (int r = 0; r < 16; ++r) { acc0[r] = 0.f; acc1[r] = 0.f; }

    // prologue: panel 0 -> buf 0
#pragma unroll
    for (int r = 0; r < 8; ++r) async_copy16(gp[r], sw + r * 256);

    int row = l & 31, half = l >> 5, rsw = row & 15;

    for (int p = 0; p < NPANEL; ++p) {
        // per-wave gate: panel p's staging complete (vmcnt(0), lgkm/exp max)
        __builtin_amdgcn_s_waitcnt(0x0F70);
        if (p + 1 < NPANEL) {                      // prefetch p+1 -> other buf
            float* dst = sw + ((p + 1) & 1) * 2048;
#pragma unroll
            for (int r = 0; r < 8; ++r)
                async_copy16(gp[r] + (p + 1) * 64, dst + r * 256);
        }
        const float* sb = sw + (p & 1) * 2048;
#pragma unroll
        for (int kk = 0; kk < 4; ++kk) {
            int c0 = kk * 4 + half * 2;
            float4 xa = *(const float4*)&sb[row * 64 + ((c0 ^ rsw) << 2)];
            float4 xb = *(const float4*)&sb[row * 64 + (((c0 + 1) ^ rsw) << 2)];
            bf16x8 a0, a1, a2;
            float xs[8] = {xa.x, xa.y, xa.z, xa.w, xb.x, xb.y, xb.z, xb.w};
#pragma unroll
            for (int j = 0; j < 8; ++j) {
                __bf16 h0, h1, h2;
                split3(xs[j], h0, h1, h2);
                a0[j] = h0; a1[j] = h1; a2[j] = h2;
            }
            int ks_abs = w * 64 + p * 4 + kk;      // absolute k-block 0..255
            const bf16x8* wp = wb + (size_t)ks_abs * 6 * 64 + l;
            bf16x8 b0 = wp[0*64], b1 = wp[1*64], b2 = wp[2*64];
            bf16x8 b3 = wp[3*64], b4 = wp[4*64], b5 = wp[5*64];
            // experts 0..31
            acc0 = __builtin_amdgcn_mfma_f32_32x32x16_bf16(a0, b0, acc0, 0, 0, 0);
            acc0 = __builtin_amdgcn_mfma_f32_32x32x16_bf16(a1, b0, acc0, 0, 0, 0);
            acc0 = __builtin_amdgcn_mfma_f32_32x32x16_bf16(a2, b0, acc0, 0, 0, 0);
            acc0 = __builtin_amdgcn_mfma_f32_32x32x16_bf16(a0, b1, acc0, 0, 0, 0);
            acc0 = __builtin_amdgcn_mfma_f32_32x32x16_bf16(a1, b1, acc0, 0, 0, 0);
            acc0 = __builtin_amdgcn_mfma_f32_32x32x16_bf16(a0, b2, acc0, 0, 0, 0);
            // experts 32..63
            acc1 = __builtin_amdgcn_mfma_f32_32x32x16_bf16(a0, b3, acc1, 0, 0, 0);
            acc1 = __builtin_amdgcn_mfma_f32_32x32x16_bf16(a1, b3, acc1, 0, 0, 0);
            acc1 = __builtin_amdgcn_mfma_f32_32x32x16_bf16(a2, b3, acc1, 0, 0, 0);
            acc1 = __builtin_amdgcn_mfma_f32_32x32x16_bf16(a0, b4, acc1, 0, 0, 0);
            acc1 = __builtin_amdgcn_mfma_f32_32x32x16_bf16(a1, b4, acc1, 0, 0, 0);
            acc1 = __builtin_amdgcn_mfma_f32_32x32x16_bf16(a0, b5, acc1, 0, 0, 0);
        }
    }

    // ---- K-reduction across the 4 waves, then in-block softmax/top-2 ----
    __syncthreads();   // all waves done with staging LDS; safe to repurpose
    // C/D layout: col = lane&31, row = (reg&3) + 8*(reg>>2) + 4*(lane>>5)
    int col = l & 31;
#pragma unroll
    for (int r = 0; r < 16; ++r) {
        int mm = (r & 3) + ((r >> 2) << 3) + (half << 2);   // row 0..31
        lds[w * 2048 + mm * 64 + col]      = acc0[r];
        lds[w * 2048 + mm * 64 + 32 + col] = acc1[r];
    }
    __syncthreads();

    // wave w handles tokens w*8 .. w*8+7; lane <-> expert
    float zacc = 0.f;
    for (int i = 0; i < 8; ++i) {
        int tl = w * 8 + i;
        float lg = lds[tl * 64 + l] + lds[2048 + tl * 64 + l]
                 + lds[4096 + tl * 64 + l] + lds[6144 + tl * 64 + l];
        zacc += lg * lg;

        float m = lg;
#pragma unroll
        for (int off = 32; off; off >>= 1) m = fmaxf(m, __shfl_xor(m, off));
        float e = expf(lg - m);
        float d = e;
#pragma unroll
        for (int off = 32; off; off >>= 1) d += __shfl_xor(d, off);
        float sc = e / d;

        float s1 = sc; int i1 = l;
#pragma unroll
        for (int off = 32; off; off >>= 1) {
            float os = __shfl_xor(s1, off); int oi = __shfl_xor(i1, off);
            if (os > s1 || (os == s1 && oi < i1)) { s1 = os; i1 = oi; }
        }
        float sm = (l == i1) ? -1.0f : sc;   // scores >= 0, -1 acts as -inf
        float s2 = sm; int i2 = l;
#pragma unroll
        for (int off = 32; off; off >>= 1) {
            float os = __shfl_xor(s2, off); int oi = __shfl_xor(i2, off);
            if (os > s2 || (os == s2 && oi < i2)) { s2 = os; i2 = oi; }
        }

        if (l == 0) {
            int t = m0 + tl;
            out[2 * t]                  = (float)i1;   // topk_idx
            out[2 * t + 1]              = (float)i2;
            out[2 * BS_TOK + 2 * t]     = s1;          // topk_scores
            out[2 * BS_TOK + 2 * t + 1] = s2;
        }
    }
    // block z partial
#pragma unroll
    for (int off = 32; off; off >>= 1) zacc += __shfl_xor(zacc, off);
    if (l == 0) zsh[w] = zacc;
    __syncthreads();
    if (tid == 0)
        zbuf[blockIdx.x] = zsh[0] + zsh[1] + zsh[2] + zsh[3];
}

// Kernel 2: reduce 512 z partials -> aux_loss (=0) and z_loss.
__global__ __launch_bounds__(256) void zreduce(const float* __restrict__ zbuf,
                                               float* __restrict__ out) {
    __shared__ float sh[4];
    int tid = threadIdx.x;
    float s = zbuf[tid] + zbuf[tid + 256];
#pragma unroll
    for (int off = 32; off; off >>= 1) s += __shfl_xor(s, off);
    if ((tid & 63) == 0) sh[tid >> 6] = s;
    __syncthreads();
    if (tid == 0) {
        out[4 * BS_TOK]     = 0.0f;  // aux_loss
        out[4 * BS_TOK + 1] = (sh[0] + sh[1] + sh[2] + sh[3])
                              * (1.0f / (float)(BS_TOK * E_DIM));
    }
}

extern "C" void kernel_launch(void* const* d_in, const int* in_sizes, int n_in,
                              void* d_out, int out_size, void* d_ws, size_t ws_size,
                              hipStream_t stream) {
    const float* x  = (const float*)d_in[0];   // [4,4096,4096] f32
    const float* gw = (const float*)d_in[1];   // [64,4096] f32
    float* out  = (float*)d_out;               // idx | scores | aux | z
    bf16x8* wb  = (bf16x8*)d_ws;                           // 1.5 MiB W frags
    float*  zbf = (float*)((char*)d_ws + WS_ZBUF_OFF);     // 2 KiB z partials

    prep_w<<<128, 256, 0, stream>>>(gw, wb);
    fused_router<<<BS_TOK / MT, 256, 0, stream>>>(x, wb, out, zbf);
    zreduce<<<1, 256, 0, stream>>>(zbf, out);
}

// Round 4
// 410.276 us; speedup vs baseline: 1.0004x; 1.0004x over previous
//
#include <hip/hip_runtime.h>
#include <hip/hip_bf16.h>

// TopKRouter: logits = x[16384,4096] @ W[64,4096]^T; softmax; top-2; z_loss.
// v4: fixes the v3 vmcnt-pollution serialization.
//   vmcnt is ISSUE-ORDERED: in v3 the W-fragment global loads were issued
//   AFTER the staging of panel p+1, so the compiler's wait before the first
//   W use forced the p+1 staging to drain -> dbuf was fully serialized.
//   v4 prefetches W frags ONE PANEL AHEAD into registers (wA/wB ping-pong),
//   issued BEFORE that panel's staging. Compute(p) consumes only loads that
//   precede staging(p+1) in issue order -> no mid-compute drain; the only
//   wait per body is the per-wave vmcnt(0) gate (hidden by compute(p-1)).
//   Panel = 32 K-floats (12 W frags/panel = 48 VGPR per buffer).
//   Everything else (fused softmax/top-2/z, no same-address atomics) kept.

typedef __bf16  bf16x8  __attribute__((ext_vector_type(8)));
typedef float   f32x16  __attribute__((ext_vector_type(16)));

#define BS_TOK 16384              // B*S tokens
#define H_DIM  4096
#define E_DIM  64
#define MT     32                 // tokens per block
#define KWAVE  1024               // K floats per wave (4 waves x 1024 = 4096)
#define PANEL  32                 // K floats per panel (2 MFMA k-steps)
#define NPANEL (KWAVE / PANEL)    // 32
#define WS_ZBUF_OFF (1536u << 10) // z partials at +1.5 MiB in d_ws

__device__ __forceinline__ void split3(float v, __bf16 &b0, __bf16 &b1, __bf16 &b2) {
    b0 = (__bf16)v;            // top 8 mantissa bits (RN)
    float r = v - (float)b0;   // exact in fp32
    b1 = (__bf16)r;            // next 8 bits
    float r2 = r - (float)b1;  // exact
    b2 = (__bf16)r2;           // v == b0+b1+b2 (within fp32)
}

__device__ __forceinline__ void async_copy16(const float* gp, float* lp) {
    __builtin_amdgcn_global_load_lds(
        (const __attribute__((address_space(1))) void*)gp,
        (__attribute__((address_space(3))) void*)lp, 16, 0, 0);
}

// Kernel 0: split gate_w into 3 bf16 terms in 32x32x16 MFMA B-frag order.
// frag f = kb*6 + nt*3 + term; element [f*64 + lane].
// lane holds W_term[n = nt*32 + (lane&31)][k = kb*16 + (lane>>5)*8 + j]
__global__ void prep_w(const float* __restrict__ gw, bf16x8* __restrict__ wb) {
    int idx  = blockIdx.x * blockDim.x + threadIdx.x;   // 0..32767
    int kb   = idx >> 7;
    int rem  = idx & 127;
    int nt   = rem >> 6;
    int lane = rem & 63;
    int n  = nt * 32 + (lane & 31);
    int kk = kb * 16 + ((lane >> 5) << 3);
    const float* p = gw + (size_t)n * H_DIM + kk;
    bf16x8 t0, t1, t2;
#pragma unroll
    for (int j = 0; j < 8; ++j) {
        __bf16 a, b, c;
        split3(p[j], a, b, c);
        t0[j] = a; t1[j] = b; t2[j] = c;
    }
    size_t fb = (size_t)(kb * 2 + nt) * 3;
    wb[(fb + 0) * 64 + lane] = t0;
    wb[(fb + 1) * 64 + lane] = t1;
    wb[(fb + 2) * 64 + lane] = t2;
}

// Kernel 1: fused router. 512 blocks x 256 thr. Wave w owns K-chunk w
// (1024 floats) of rows m0..m0+31. Panel = 32 rows x 32 floats staged as
// 4 async 1-KiB calls (8 rows x 128 B contiguous each); 16-B chunk c of
// row g lands at slot c ^ (g&7) -> frag ds_read_b128 at the 8-lane/quad
// structural floor. LDS: 4 waves x dbuf(2 x 1024 floats) = 32 KiB.
__global__ __launch_bounds__(256, 2) void fused_router(
        const float* __restrict__ x, const bf16x8* __restrict__ wb,
        float* __restrict__ out, float* __restrict__ zbuf) {
    __shared__ float lds[8192];    // staging; repurposed for final reduce
    __shared__ float zsh[4];

    int tid = threadIdx.x;
    int w   = tid >> 6;            // wave 0..3 (owns K-chunk w)
    int l   = tid & 63;
    int m0  = blockIdx.x * MT;
    float* sw = &lds[w * 2048];    // this wave's staging dbuf

    // staging pointers: call r covers rows 8r..8r+7, 8 chunks of 16 B each
    const float* gp[4];
#pragma unroll
    for (int r = 0; r < 4; ++r) {
        int g = 8 * r + (l >> 3);                  // row in tile 0..31
        int c = (l & 7) ^ (g & 7);                 // swizzled global chunk
        gp[r] = x + (size_t)(m0 + g) * H_DIM + w * KWAVE + c * 4;
    }

    f32x16 acc0, acc1;
#pragma unroll
    for (int r = 0; r < 16; ++r) { acc0[r] = 0.f; acc1[r] = 0.f; }

    // W frag loader: panel p needs k-blocks (w*64 + 2p, +1) -> 12 frags
    const bf16x8* wbl = wb + l;
    auto loadW = [&](int p, bf16x8* wf) {
        const bf16x8* wp = wbl + (size_t)(w * 64 + p * 2) * 6 * 64;
#pragma unroll
        for (int i = 0; i < 12; ++i) wf[i] = wp[i * 64];
    };

    int row = l & 31, half = l >> 5, rsw = (l & 31) & 7;

    // compute one panel from LDS buffer sb with W regs wf
    auto compute = [&](const float* sb, const bf16x8* wf) {
#pragma unroll
        for (int s = 0; s < 2; ++s) {
            int c0 = s * 4 + half * 2;
            float4 xa = *(const float4*)&sb[row * 32 + ((c0 ^ rsw) << 2)];
            float4 xb = *(const float4*)&sb[row * 32 + (((c0 + 1) ^ rsw) << 2)];
            bf16x8 a0, a1, a2;
            float xs[8] = {xa.x, xa.y, xa.z, xa.w, xb.x, xb.y, xb.z, xb.w};
#pragma unroll
            for (int j = 0; j < 8; ++j) {
                __bf16 h0, h1, h2;
                split3(xs[j], h0, h1, h2);
                a0[j] = h0; a1[j] = h1; a2[j] = h2;
            }
            bf16x8 b0 = wf[s*6+0], b1 = wf[s*6+1], b2 = wf[s*6+2];
            bf16x8 b3 = wf[s*6+3], b4 = wf[s*6+4], b5 = wf[s*6+5];
            // experts 0..31
            acc0 = __builtin_amdgcn_mfma_f32_32x32x16_bf16(a0, b0, acc0, 0, 0, 0);
            acc0 = __builtin_amdgcn_mfma_f32_32x32x16_bf16(a1, b0, acc0, 0, 0, 0);
            acc0 = __builtin_amdgcn_mfma_f32_32x32x16_bf16(a2, b0, acc0, 0, 0, 0);
            acc0 = __builtin_amdgcn_mfma_f32_32x32x16_bf16(a0, b1, acc0, 0, 0, 0);
            acc0 = __builtin_amdgcn_mfma_f32_32x32x16_bf16(a1, b1, acc0, 0, 0, 0);
            acc0 = __builtin_amdgcn_mfma_f32_32x32x16_bf16(a0, b2, acc0, 0, 0, 0);
            // experts 32..63
            acc1 = __builtin_amdgcn_mfma_f32_32x32x16_bf16(a0, b3, acc1, 0, 0, 0);
            acc1 = __builtin_amdgcn_mfma_f32_32x32x16_bf16(a1, b3, acc1, 0, 0, 0);
            acc1 = __builtin_amdgcn_mfma_f32_32x32x16_bf16(a2, b3, acc1, 0, 0, 0);
            acc1 = __builtin_amdgcn_mfma_f32_32x32x16_bf16(a0, b4, acc1, 0, 0, 0);
            acc1 = __builtin_amdgcn_mfma_f32_32x32x16_bf16(a1, b4, acc1, 0, 0, 0);
            acc1 = __builtin_amdgcn_mfma_f32_32x32x16_bf16(a0, b5, acc1, 0, 0, 0);
        }
    };

    // one pipeline body: gate panel P; prefetch W(P+1) + stage(P+1); compute P
    bf16x8 wA[12], wB[12];
    auto body = [&](int P, bf16x8* WC, bf16x8* WN) {
        __builtin_amdgcn_s_waitcnt(0x0F70);   // vmcnt(0): panel P + WC ready
        if (P + 1 < NPANEL) {
            loadW(P + 1, WN);                 // W prefetch BEFORE staging issue
            float* dst = sw + ((P + 1) & 1) * 1024;
#pragma unroll
            for (int r = 0; r < 4; ++r)
                async_copy16(gp[r] + (P + 1) * 32, dst + r * 256);
        }
        compute(sw + (P & 1) * 1024, WC);
    };

    // prologue: stage panel 0 + load W(0)
#pragma unroll
    for (int r = 0; r < 4; ++r) async_copy16(gp[r], sw + r * 256);
    loadW(0, wA);

    for (int p = 0; p < NPANEL; p += 2) {
        body(p,     wA, wB);
        body(p + 1, wB, wA);
    }

    // ---- K-reduction across the 4 waves, then in-block softmax/top-2 ----
    __syncthreads();   // all waves done with staging LDS; safe to repurpose
    // C/D layout: col = lane&31, row = (reg&3) + 8*(reg>>2) + 4*(lane>>5)
    int col = l & 31;
#pragma unroll
    for (int r = 0; r < 16; ++r) {
        int mm = (r & 3) + ((r >> 2) << 3) + (half << 2);   // row 0..31
        lds[w * 2048 + mm * 64 + col]      = acc0[r];
        lds[w * 2048 + mm * 64 + 32 + col] = acc1[r];
    }
    __syncthreads();

    // wave w handles tokens w*8 .. w*8+7; lane <-> expert
    float zacc = 0.f;
    for (int i = 0; i < 8; ++i) {
        int tl = w * 8 + i;
        float lg = lds[tl * 64 + l] + lds[2048 + tl * 64 + l]
                 + lds[4096 + tl * 64 + l] + lds[6144 + tl * 64 + l];
        zacc += lg * lg;

        float m = lg;
#pragma unroll
        for (int off = 32; off; off >>= 1) m = fmaxf(m, __shfl_xor(m, off));
        float e = expf(lg - m);
        float d = e;
#pragma unroll
        for (int off = 32; off; off >>= 1) d += __shfl_xor(d, off);
        float sc = e / d;

        float s1 = sc; int i1 = l;
#pragma unroll
        for (int off = 32; off; off >>= 1) {
            float os = __shfl_xor(s1, off); int oi = __shfl_xor(i1, off);
            if (os > s1 || (os == s1 && oi < i1)) { s1 = os; i1 = oi; }
        }
        float sm = (l == i1) ? -1.0f : sc;   // scores >= 0, -1 acts as -inf
        float s2 = sm; int i2 = l;
#pragma unroll
        for (int off = 32; off; off >>= 1) {
            float os = __shfl_xor(s2, off); int oi = __shfl_xor(i2, off);
            if (os > s2 || (os == s2 && oi < i2)) { s2 = os; i2 = oi; }
        }

        if (l == 0) {
            int t = m0 + tl;
            out[2 * t]                  = (float)i1;   // topk_idx
            out[2 * t + 1]              = (float)i2;
            out[2 * BS_TOK + 2 * t]     = s1;          // topk_scores
            out[2 * BS_TOK + 2 * t + 1] = s2;
        }
    }
    // block z partial
#pragma unroll
    for (int off = 32; off; off >>= 1) zacc += __shfl_xor(zacc, off);
    if (l == 0) zsh[w] = zacc;
    __syncthreads();
    if (tid == 0)
        zbuf[blockIdx.x] = zsh[0] + zsh[1] + zsh[2] + zsh[3];
}

// Kernel 2: reduce 512 z partials -> aux_loss (=0) and z_loss.
__global__ __launch_bounds__(256) void zreduce(const float* __restrict__ zbuf,
                                               float* __restrict__ out) {
    __shared__ float sh[4];
    int tid = threadIdx.x;
    float s = zbuf[tid] + zbuf[tid + 256];
#pragma unroll
    for (int off = 32; off; off >>= 1) s += __shfl_xor(s, off);
    if ((tid & 63) == 0) sh[tid >> 6] = s;
    __syncthreads();
    if (tid == 0) {
        out[4 * BS_TOK]     = 0.0f;  // aux_loss
        out[4 * BS_TOK + 1] = (sh[0] + sh[1] + sh[2] + sh[3])
                              * (1.0f / (float)(BS_TOK * E_DIM));
    }
}

extern "C" void kernel_launch(void* const* d_in, const int* in_sizes, int n_in,
                              void* d_out, int out_size, void* d_ws, size_t ws_size,
                              hipStream_t stream) {
    const float* x  = (const float*)d_in[0];   // [4,4096,4096] f32
    const float* gw = (const float*)d_in[1];   // [64,4096] f32
    float* out  = (float*)d_out;               // idx | scores | aux | z
    bf16x8* wb  = (bf16x8*)d_ws;                           // 1.5 MiB W frags
    float*  zbf = (float*)((char*)d_ws + WS_ZBUF_OFF);     // 2 KiB z partials

    prep_w<<<128, 256, 0, stream>>>(gw, wb);
    fused_router<<<BS_TOK / MT, 256, 0, stream>>>(x, wb, out, zbf);
    zreduce<<<1, 256, 0, stream>>>(zbf, out);
}